// Round 1
// baseline (44.146 us; speedup 1.0000x reference)
//
#include <hip/hip_runtime.h>

// HaarDecomposition2D: 9 levels of a per-4x4-block diagonal Haar transform.
// Input  (8,3,512,512) f32 ; Output (8,30,512,512) f32
// Each 4x4 block is fully independent across all 9 levels (two cascaded 2x2
// diagonal Haar stages + adjoint upsample stay inside the block; the four
// orientation branches tile the 16 positions exactly once each).

#define HAAR_S 0.5f

__global__ __launch_bounds__(256) void haar9_kernel(const float* __restrict__ x,
                                                    float* __restrict__ out) {
    // 24 images (b*3+c), each 128x128 blocks of 4x4.
    const int tid = blockIdx.x * blockDim.x + threadIdx.x;   // 0 .. 393215
    const int bw  = tid & 127;          // block col
    const int bh  = (tid >> 7) & 127;   // block row
    const int img = tid >> 14;          // 0..23 = b*3 + c
    const int b   = img / 3;
    const int c   = img - 3 * b;

    const float* xin = x + ((size_t)img * 512 + 4 * (size_t)bh) * 512 + 4 * (size_t)bw;

    float v[4][4];
#pragma unroll
    for (int r = 0; r < 4; ++r) {
        float4 t = *(const float4*)(xin + (size_t)r * 512);
        v[r][0] = t.x; v[r][1] = t.y; v[r][2] = t.z; v[r][3] = t.w;
    }

    // out channel layout: b*30 + 3*k + c for detail level k, b*30 + 27 + c for low
    const size_t chanStride = (size_t)512 * 512;
    const size_t outBase = ((size_t)(b * 30 + c) * 512 + 4 * (size_t)bh) * 512 + 4 * (size_t)bw;

#pragma unroll
    for (int k = 0; k < 9; ++k) {
        // first Haar stage (2x2 sub-blocks)
        const float ud00 = HAAR_S * (v[0][1] + v[1][0]);
        const float ud01 = HAAR_S * (v[0][3] + v[1][2]);
        const float ud10 = HAAR_S * (v[2][1] + v[3][0]);
        const float ud11 = HAAR_S * (v[2][3] + v[3][2]);
        const float dd00 = HAAR_S * (v[0][0] + v[1][1]);
        const float dd01 = HAAR_S * (v[0][2] + v[1][3]);
        const float dd10 = HAAR_S * (v[2][0] + v[3][1]);
        const float dd11 = HAAR_S * (v[2][2] + v[3][3]);

        // second Haar stage (2x2 of first-stage lows)
        const float uu_l = HAAR_S * (ud01 + ud10), uu_d = HAAR_S * (ud01 - ud10);
        const float du_l = HAAR_S * (ud00 + ud11), du_d = HAAR_S * (ud00 - ud11);
        const float dd_l = HAAR_S * (dd00 + dd11), dd_d = HAAR_S * (dd00 - dd11);
        const float ud_l = HAAR_S * (dd01 + dd10), ud_d = HAAR_S * (dd01 - dd10);

        // scatter pattern (position -> branch):
        // row0: [dd, du, ud, uu]   row1: [du, dd, uu, ud]
        // row2: [ud, uu, dd, du]   row3: [uu, ud, du, dd]
        float* det = out + outBase + (size_t)(3 * k) * chanStride;
        *(float4*)(det + 0 * 512) = make_float4(dd_d, du_d, ud_d, uu_d);
        *(float4*)(det + 1 * 512) = make_float4(du_d, dd_d, uu_d, ud_d);
        *(float4*)(det + 2 * 512) = make_float4(ud_d, uu_d, dd_d, du_d);
        *(float4*)(det + 3 * 512) = make_float4(uu_d, ud_d, du_d, dd_d);

        // new low block becomes next level's input
        v[0][0] = dd_l; v[0][1] = du_l; v[0][2] = ud_l; v[0][3] = uu_l;
        v[1][0] = du_l; v[1][1] = dd_l; v[1][2] = uu_l; v[1][3] = ud_l;
        v[2][0] = ud_l; v[2][1] = uu_l; v[2][2] = dd_l; v[2][3] = du_l;
        v[3][0] = uu_l; v[3][1] = ud_l; v[3][2] = du_l; v[3][3] = dd_l;
    }

    float* lw = out + outBase + (size_t)27 * chanStride;
#pragma unroll
    for (int r = 0; r < 4; ++r) {
        *(float4*)(lw + (size_t)r * 512) = make_float4(v[r][0], v[r][1], v[r][2], v[r][3]);
    }
}

extern "C" void kernel_launch(void* const* d_in, const int* in_sizes, int n_in,
                              void* d_out, int out_size, void* d_ws, size_t ws_size,
                              hipStream_t stream) {
    const float* x = (const float*)d_in[0];
    float* out = (float*)d_out;
    // 8*3*128*128 = 393216 threads, one per 4x4 block
    const int total = 393216;
    const int block = 256;
    const int grid = total / block;  // 1536
    haar9_kernel<<<grid, block, 0, stream>>>(x, out);
}